// Round 8
// baseline (120.837 us; speedup 1.0000x reference)
//
#include <hip/hip_runtime.h>

#define NQ 2048
#define NO 2048
#define NOC 32   // o-chunks of 64

// ws layout (float offsets):
// T  [NO][64]       : t[o][l] = pos_o . (W1[3:6]-W1[6:9])   (512 KB)
// Ph [NOC][NQ][64]  : unnormalized h partials (pre-Wv)
// Ps [NOC][NQ]      : softmax-denominator partials
constexpr size_t OFF_T  = 0;
constexpr size_t OFF_PH = (size_t)NO * 64;
constexpr size_t OFF_PS = OFF_PH + (size_t)NOC * NQ * 64;

// ---------------------------------------------------------------------------
// Prep: T[o][l]. 512 blocks x 256 thr; gid -> o = gid>>6, l = gid&63.
// ---------------------------------------------------------------------------
__global__ __launch_bounds__(256) void gano_prep(
    const float* __restrict__ pos_obs,
    const float* __restrict__ W1,
    float* __restrict__ T)
{
    int gid = blockIdx.x * 256 + threadIdx.x;
    int o = gid >> 6, l = gid & 63;
    float po0 = pos_obs[o * 3 + 0], po1 = pos_obs[o * 3 + 1], po2 = pos_obs[o * 3 + 2];
    float w3 = W1[3 * 64 + l], w4 = W1[4 * 64 + l], w5 = W1[5 * 64 + l];
    float w6 = W1[6 * 64 + l], w7 = W1[7 * 64 + l], w8 = W1[8 * 64 + l];
    T[(size_t)o * 64 + l] = po0 * (w3 - w6) + po1 * (w4 - w7) + po2 * (w5 - w8);
}

// ---------------------------------------------------------------------------
// Main: 1024 blocks = 32 q-groups x 32 o-chunks(64). lane = q.
// All wave-uniform operands (t-rows, W2, pos_o, h_obs rows) go through the
// SCALAR pipe: readfirstlane-uniform offsets -> s_load -> SGPR src operands.
// This empties the LDS pipe (R7's bottleneck: 272 ds_read_b128/wave, ~22 us
// of CU LDS-pipe time) — LDS now carries only the 64-b32 e-exchange.
// u[64] in VGPRs: phase role-switch keeps peak live regs ~100 < 128 budget.
// Phase A: wave w -> o-slice [16w,+16), per-o serial logit accumulation.
// Phase B: wave w -> l-slice [16w,+16), all 64 o; raw h_obs rows (Wv applied
// post-normalize in comb). One barrier total; no atomics; disjoint outputs.
// ---------------------------------------------------------------------------
__global__ __launch_bounds__(256, 4) void gano_main(
    const float* __restrict__ T,
    const float* __restrict__ h_obs,
    const float* __restrict__ pos_obs,
    const float* __restrict__ pos_query,
    const float* __restrict__ W1,
    const float* __restrict__ b1,
    const float* __restrict__ W2,
    float* __restrict__ Ph,
    float* __restrict__ Ps)
{
    __shared__ float ue[64 * 64];   // e [o][q-lane]; (o*64+lane)%32 = lane%32 -> 2-way = free
    __shared__ float sbuf[4 * 64];

    const int tid  = threadIdx.x;
    const int lane = tid & 63;
    const int wave = __builtin_amdgcn_readfirstlane(tid >> 6);
    const int qg = blockIdx.x >> 5;   // 0..31
    const int oc = blockIdx.x & 31;   // 0..31
    const int obase = oc * 64;
    const int q  = qg * 64 + lane;
    const int ow = wave * 16;

    float pq0 = pos_query[q * 3 + 0];
    float pq1 = pos_query[q * 3 + 1];
    float pq2 = pos_query[q * 3 + 2];

    // ---- u[64] in VGPRs: 6 fma + 1 add per l; W1/b1 reads are uniform ->
    //      scalar loads; each VALU op uses at most 1 SGPR operand. ----
    float u[64];
#pragma unroll
    for (int l = 0; l < 64; ++l) {
        float a = b1[l];
        a += pq0 * W1[0 * 64 + l];
        a += pq1 * W1[1 * 64 + l];
        a += pq2 * W1[2 * 64 + l];
        a += pq0 * W1[6 * 64 + l];
        a += pq1 * W1[7 * 64 + l];
        a += pq2 * W1[8 * 64 + l];
        u[l] = a;
    }

    // ---- Phase A: per-o logit, mask, exp; e -> LDS ----
    float spart = 0.f;
#pragma unroll 2
    for (int o = 0; o < 16; ++o) {
        const int toff = __builtin_amdgcn_readfirstlane((obase + ow + o) * 64);
        const float* __restrict__ trow = T + toff;     // uniform -> s_load
        float a0 = 0.f, a1 = 0.f, a2 = 0.f, a3 = 0.f;
#pragma unroll
        for (int l = 0; l < 64; l += 4) {
            a0 += W2[l + 0] * fmaxf(u[l + 0] + trow[l + 0], 0.f);
            a1 += W2[l + 1] * fmaxf(u[l + 1] + trow[l + 1], 0.f);
            a2 += W2[l + 2] * fmaxf(u[l + 2] + trow[l + 2], 0.f);
            a3 += W2[l + 3] * fmaxf(u[l + 3] + trow[l + 3], 0.f);
        }
        float lgo = (a0 + a1) + (a2 + a3);
        const int poff = __builtin_amdgcn_readfirstlane((obase + ow + o) * 3);
        float d0 = pq0 - pos_obs[poff + 0];            // uniform -> s_load
        float d1 = pq1 - pos_obs[poff + 1];
        float d2 = pq2 - pos_obs[poff + 2];
        float dd = d0 * d0 + d1 * d1 + d2 * d2;
        float ev = (dd > 0.25f) ? 0.f : __expf(lgo);   // logits O(1): raw exp safe
        spart += ev;
        ue[(ow + o) * 64 + lane] = ev;
    }
    sbuf[wave * 64 + lane] = spart;
    __syncthreads();   // the kernel's only barrier

    // ---- Phase B: wave w -> l-slice [16w,+16), all 64 o, raw h_obs rows ----
    float h0 = 0.f, h1 = 0.f, h2 = 0.f, h3 = 0.f, h4 = 0.f, h5 = 0.f, h6 = 0.f, h7 = 0.f;
    float h8 = 0.f, h9 = 0.f, hA = 0.f, hB = 0.f, hC = 0.f, hD = 0.f, hE = 0.f, hF = 0.f;
#pragma unroll 2
    for (int o = 0; o < 64; ++o) {
        float eo = ue[o * 64 + lane];                  // b32, 2-way = free
        const int hoff = __builtin_amdgcn_readfirstlane((obase + o) * 64 + ow);
        const float* __restrict__ hr = h_obs + hoff;   // uniform -> s_load (16 floats)
        h0 += eo * hr[0];  h1 += eo * hr[1];  h2 += eo * hr[2];  h3 += eo * hr[3];
        h4 += eo * hr[4];  h5 += eo * hr[5];  h6 += eo * hr[6];  h7 += eo * hr[7];
        h8 += eo * hr[8];  h9 += eo * hr[9];  hA += eo * hr[10]; hB += eo * hr[11];
        hC += eo * hr[12]; hD += eo * hr[13]; hE += eo * hr[14]; hF += eo * hr[15];
    }

    // ---- stores: disjoint per wave, coalesced float4 ----
    float* hp = Ph + ((size_t)oc * NQ + (size_t)qg * 64 + lane) * 64 + ow;
    ((float4*)hp)[0] = make_float4(h0, h1, h2, h3);
    ((float4*)hp)[1] = make_float4(h4, h5, h6, h7);
    ((float4*)hp)[2] = make_float4(h8, h9, hA, hB);
    ((float4*)hp)[3] = make_float4(hC, hD, hE, hF);
    if (wave == 0) {
        float s = sbuf[lane] + sbuf[64 + lane] + sbuf[128 + lane] + sbuf[192 + lane];
        Ps[(size_t)oc * NQ + (size_t)qg * 64 + lane] = s;
    }
}

// ---------------------------------------------------------------------------
// Combine + Wv projection: g[q][k] = sum_c Ph[c][q][k]; s = sum_c Ps[c][q];
// out[q][l] = (g[q][:]/s) @ Wv + bv.  512 blocks; block = 4 q; wave w owns
// query w; Wv staged in LDS (lane-consecutive b32, conflict-free).
// ---------------------------------------------------------------------------
__global__ __launch_bounds__(256, 2) void gano_comb(
    const float* __restrict__ Ph,
    const float* __restrict__ Ps,
    const float* __restrict__ Wv,
    const float* __restrict__ bv,
    float* __restrict__ out)
{
    __shared__ __align__(16) float wv[64 * 64];
    __shared__ __align__(16) float g[4 * 68];
    const int tid  = threadIdx.x;
    const int lane = tid & 63;
    const int wave = tid >> 6;
    const int q0 = blockIdx.x * 4;
    {
        const float4* src = (const float4*)Wv;
        float4* dst = (float4*)wv;
#pragma unroll
        for (int k = 0; k < 4; ++k) dst[tid + k * 256] = src[tid + k * 256];
    }
    {
        const int qi = wave, k = lane;
        float acc = 0.f;
#pragma unroll
        for (int c = 0; c < NOC; ++c)
            acc += Ph[((size_t)c * NQ + q0 + qi) * 64 + k];
        g[qi * 68 + k] = acc;
        if (k == 0) {
            float ss = 0.f;
#pragma unroll
            for (int c = 0; c < NOC; ++c) ss += Ps[(size_t)c * NQ + q0 + qi];
            g[qi * 68 + 64] = ss;
        }
    }
    __syncthreads();
    const float* gq = g + wave * 68;            // wave-uniform broadcast
    float inv = 1.0f / gq[64];
    float a0 = 0.f, a1 = 0.f, a2 = 0.f, a3 = 0.f;
#pragma unroll
    for (int kb = 0; kb < 16; ++kb) {
        float4 g4 = *(const float4*)(gq + kb * 4);
        a0 += g4.x * wv[(kb * 4 + 0) * 64 + lane];
        a1 += g4.y * wv[(kb * 4 + 1) * 64 + lane];
        a2 += g4.z * wv[(kb * 4 + 2) * 64 + lane];
        a3 += g4.w * wv[(kb * 4 + 3) * 64 + lane];
    }
    out[(size_t)(q0 + wave) * 64 + lane] = ((a0 + a1) + (a2 + a3)) * inv + bv[lane];
}

// ---------------------------------------------------------------------------
extern "C" void kernel_launch(void* const* d_in, const int* in_sizes, int n_in,
                              void* d_out, int out_size, void* d_ws, size_t ws_size,
                              hipStream_t stream) {
    const float* h_obs     = (const float*)d_in[0];
    // d_in[1] = x_obs (unused by reference)
    const float* pos_obs   = (const float*)d_in[2];
    const float* pos_query = (const float*)d_in[3];
    const float* W1        = (const float*)d_in[4];
    const float* b1        = (const float*)d_in[5];
    const float* W2        = (const float*)d_in[6];
    // d_in[7] = b2: constant shift, cancels in softmax
    const float* Wv        = (const float*)d_in[8];
    const float* bv        = (const float*)d_in[9];
    float* ws  = (float*)d_ws;
    float* out = (float*)d_out;

    gano_prep<<<dim3(NO * 64 / 256), dim3(256), 0, stream>>>(pos_obs, W1, ws + OFF_T);
    gano_main<<<dim3(1024), dim3(256), 0, stream>>>(ws + OFF_T, h_obs, pos_obs, pos_query,
                                                    W1, b1, W2, ws + OFF_PH, ws + OFF_PS);
    gano_comb<<<dim3(NQ / 4), dim3(256), 0, stream>>>(ws + OFF_PH, ws + OFF_PS, Wv, bv, out);
}

// Round 9
// 117.683 us; speedup vs baseline: 1.0268x; 1.0268x over previous
//
#include <hip/hip_runtime.h>

#define NQ 2048
#define NO 2048
#define NOC 32   // o-chunks of 64

// ws layout (float offsets):
// Tt [64 l][NO o]   : t transposed; t[o][l] = pos_o . (W1[3:6]-W1[6:9])
// Ph [NOC][NQ][64]  : unnormalized h partials (pre-Wv)
// Ps [NOC][NQ]      : softmax-denominator partials
constexpr size_t OFF_TT = 0;
constexpr size_t OFF_PH = (size_t)64 * NO;
constexpr size_t OFF_PS = OFF_PH + (size_t)NOC * NQ * 64;

// ---------------------------------------------------------------------------
// Prep: Tt[l][o]. 512 blocks x 256 thr; idx -> o = idx & 2047 (coalesced),
// l = idx >> 11 (uniform within block) -> coalesced stores.
// ---------------------------------------------------------------------------
__global__ __launch_bounds__(256) void gano_prep(
    const float* __restrict__ pos_obs,
    const float* __restrict__ W1,
    float* __restrict__ Tt)
{
    int idx = blockIdx.x * 256 + threadIdx.x;
    int o = idx & (NO - 1);
    int l = idx >> 11;
    float po0 = pos_obs[o * 3 + 0], po1 = pos_obs[o * 3 + 1], po2 = pos_obs[o * 3 + 2];
    float w3 = W1[3 * 64 + l], w4 = W1[4 * 64 + l], w5 = W1[5 * 64 + l];
    float w6 = W1[6 * 64 + l], w7 = W1[7 * 64 + l], w8 = W1[8 * 64 + l];
    Tt[(size_t)l * NO + o] = po0 * (w3 - w6) + po1 * (w4 - w7) + po2 * (w5 - w8);
}

// ---------------------------------------------------------------------------
// Main: 1024 blocks = 32 q-groups x 32 o-chunks(64). lane = q.
// AGPR-trap avoidance (R5/R8 lesson): NO per-lane array larger than 16 —
//   u[64] -> LDS [lb][q] float4 tile (16 ds_read_b128/wave in phase A)
//   t     -> scalar pipe: Tt[l][o..o+16] s_load_dwordx16 per l (SGPR operands)
// LDS pipe load/wave: 16 b128 + 80 b32 (R7 had 272 b128 => ~22 us chip LDS time).
// Phase A: wave w -> o-slice [16w,+16); lb-outer, o-inner, lg[16] in VGPRs.
// Phase B: wave w -> l-slice [16w,+16), all 64 o; raw h_obs rows via s_load
// (Wv applied post-normalize in comb). Disjoint outputs; no atomics.
// ---------------------------------------------------------------------------
__global__ __launch_bounds__(256, 4) void gano_main(
    const float* __restrict__ Tt,
    const float* __restrict__ h_obs,
    const float* __restrict__ pos_obs,
    const float* __restrict__ pos_query,
    const float* __restrict__ W1,
    const float* __restrict__ b1,
    const float* __restrict__ W2,
    float* __restrict__ Ph,
    float* __restrict__ Ps)
{
    __shared__ __align__(16) float ut[16 * 64 * 4];  // u4 [lb][q-lane]
    __shared__ float ue[64 * 64];                    // e [o][q-lane]
    __shared__ float sbuf[4 * 64];

    const int tid  = threadIdx.x;
    const int lane = tid & 63;
    const int wave = __builtin_amdgcn_readfirstlane(tid >> 6);
    const int qg = blockIdx.x >> 5;   // 0..31
    const int oc = blockIdx.x & 31;   // 0..31
    const int obase = oc * 64;
    const int q  = qg * 64 + lane;
    const int ow = wave * 16;

    float pq0 = pos_query[q * 3 + 0];
    float pq1 = pos_query[q * 3 + 1];
    float pq2 = pos_query[q * 3 + 2];

    // ---- u-tile: wave w computes lb in [4w,4w+4); W1/b1 uniform -> s_load;
    //      each fma uses 1 SGPR + per-lane pq (VGPR). No u register array. ----
#pragma unroll
    for (int k = 0; k < 4; ++k) {
        const int lb = wave * 4 + k;
        float4 uv;
        {
            const int l = lb * 4;
            uv.x = b1[l+0] + pq0*W1[l+0] + pq1*W1[64+l+0] + pq2*W1[128+l+0]
                 + pq0*W1[384+l+0] + pq1*W1[448+l+0] + pq2*W1[512+l+0];
            uv.y = b1[l+1] + pq0*W1[l+1] + pq1*W1[64+l+1] + pq2*W1[128+l+1]
                 + pq0*W1[384+l+1] + pq1*W1[448+l+1] + pq2*W1[512+l+1];
            uv.z = b1[l+2] + pq0*W1[l+2] + pq1*W1[64+l+2] + pq2*W1[128+l+2]
                 + pq0*W1[384+l+2] + pq1*W1[448+l+2] + pq2*W1[512+l+2];
            uv.w = b1[l+3] + pq0*W1[l+3] + pq1*W1[64+l+3] + pq2*W1[128+l+3]
                 + pq0*W1[384+l+3] + pq1*W1[448+l+3] + pq2*W1[512+l+3];
        }
        *(float4*)(ut + (size_t)(lb * 64 + lane) * 4) = uv;
    }
    __syncthreads();   // sync1: u-tile ready

    // ---- Phase A: wave w -> o-slice [16w,+16); lb-outer, o-inner ----
    float lg[16];
#pragma unroll
    for (int o = 0; o < 16; ++o) lg[o] = 0.f;
#pragma unroll
    for (int lb = 0; lb < 16; ++lb) {
        float4 u4 = *(const float4*)(ut + (size_t)(lb * 64 + lane) * 4);  // b128, conflict-free
#pragma unroll
        for (int dl = 0; dl < 4; ++dl) {
            const int l = lb * 4 + dl;
            const int toff = __builtin_amdgcn_readfirstlane(l * NO + obase + ow);
            const float* __restrict__ tr = Tt + toff;   // uniform -> s_load_dwordx16
            const float ul = (dl == 0) ? u4.x : (dl == 1) ? u4.y : (dl == 2) ? u4.z : u4.w;
            const float wl = W2[l];                      // uniform -> SGPR
#pragma unroll
            for (int o = 0; o < 16; ++o)
                lg[o] += wl * fmaxf(ul + tr[o], 0.f);    // add(1 sgpr) + max + fma(1 sgpr)
        }
    }
    // ---- mask + exp; e -> LDS ----
    float spart = 0.f;
#pragma unroll
    for (int o = 0; o < 16; ++o) {
        const int poff = __builtin_amdgcn_readfirstlane((obase + ow + o) * 3);
        float d0 = pq0 - pos_obs[poff + 0];              // uniform -> s_load
        float d1 = pq1 - pos_obs[poff + 1];
        float d2 = pq2 - pos_obs[poff + 2];
        float dd = d0 * d0 + d1 * d1 + d2 * d2;
        float ev = (dd > 0.25f) ? 0.f : __expf(lg[o]);   // logits O(1): raw exp safe
        spart += ev;
        ue[(ow + o) * 64 + lane] = ev;                   // lane-consecutive, conflict-free
    }
    sbuf[wave * 64 + lane] = spart;
    __syncthreads();   // sync2: e-buffer ready

    // ---- Phase B: wave w -> l-slice [16w,+16), all 64 o, raw h_obs rows ----
    float h0 = 0.f, h1 = 0.f, h2 = 0.f, h3 = 0.f, h4 = 0.f, h5 = 0.f, h6 = 0.f, h7 = 0.f;
    float h8 = 0.f, h9 = 0.f, hA = 0.f, hB = 0.f, hC = 0.f, hD = 0.f, hE = 0.f, hF = 0.f;
#pragma unroll 2
    for (int o = 0; o < 64; ++o) {
        float eo = ue[o * 64 + lane];                    // b32, conflict-free
        const int hoff = __builtin_amdgcn_readfirstlane((obase + o) * 64 + ow);
        const float* __restrict__ hr = h_obs + hoff;     // uniform -> s_load (16 floats)
        h0 += eo * hr[0];  h1 += eo * hr[1];  h2 += eo * hr[2];  h3 += eo * hr[3];
        h4 += eo * hr[4];  h5 += eo * hr[5];  h6 += eo * hr[6];  h7 += eo * hr[7];
        h8 += eo * hr[8];  h9 += eo * hr[9];  hA += eo * hr[10]; hB += eo * hr[11];
        hC += eo * hr[12]; hD += eo * hr[13]; hE += eo * hr[14]; hF += eo * hr[15];
    }

    // ---- stores: disjoint per wave, coalesced float4 ----
    float* hp = Ph + ((size_t)oc * NQ + (size_t)qg * 64 + lane) * 64 + ow;
    ((float4*)hp)[0] = make_float4(h0, h1, h2, h3);
    ((float4*)hp)[1] = make_float4(h4, h5, h6, h7);
    ((float4*)hp)[2] = make_float4(h8, h9, hA, hB);
    ((float4*)hp)[3] = make_float4(hC, hD, hE, hF);
    if (wave == 0) {
        float s = sbuf[lane] + sbuf[64 + lane] + sbuf[128 + lane] + sbuf[192 + lane];
        Ps[(size_t)oc * NQ + (size_t)qg * 64 + lane] = s;
    }
}

// ---------------------------------------------------------------------------
// Combine + Wv projection: g[q][k] = sum_c Ph[c][q][k]; s = sum_c Ps[c][q];
// out[q][l] = (g[q][:]/s) @ Wv + bv.  512 blocks; block = 4 q; wave w owns
// query w; Wv staged in LDS (lane-consecutive b32, conflict-free).
// ---------------------------------------------------------------------------
__global__ __launch_bounds__(256, 2) void gano_comb(
    const float* __restrict__ Ph,
    const float* __restrict__ Ps,
    const float* __restrict__ Wv,
    const float* __restrict__ bv,
    float* __restrict__ out)
{
    __shared__ __align__(16) float wv[64 * 64];
    __shared__ __align__(16) float g[4 * 68];
    const int tid  = threadIdx.x;
    const int lane = tid & 63;
    const int wave = tid >> 6;
    const int q0 = blockIdx.x * 4;
    {
        const float4* src = (const float4*)Wv;
        float4* dst = (float4*)wv;
#pragma unroll
        for (int k = 0; k < 4; ++k) dst[tid + k * 256] = src[tid + k * 256];
    }
    {
        const int qi = wave, k = lane;
        float acc = 0.f;
#pragma unroll
        for (int c = 0; c < NOC; ++c)
            acc += Ph[((size_t)c * NQ + q0 + qi) * 64 + k];
        g[qi * 68 + k] = acc;
        if (k == 0) {
            float ss = 0.f;
#pragma unroll
            for (int c = 0; c < NOC; ++c) ss += Ps[(size_t)c * NQ + q0 + qi];
            g[qi * 68 + 64] = ss;
        }
    }
    __syncthreads();
    const float* gq = g + wave * 68;            // wave-uniform broadcast
    float inv = 1.0f / gq[64];
    float a0 = 0.f, a1 = 0.f, a2 = 0.f, a3 = 0.f;
#pragma unroll
    for (int kb = 0; kb < 16; ++kb) {
        float4 g4 = *(const float4*)(gq + kb * 4);
        a0 += g4.x * wv[(kb * 4 + 0) * 64 + lane];
        a1 += g4.y * wv[(kb * 4 + 1) * 64 + lane];
        a2 += g4.z * wv[(kb * 4 + 2) * 64 + lane];
        a3 += g4.w * wv[(kb * 4 + 3) * 64 + lane];
    }
    out[(size_t)(q0 + wave) * 64 + lane] = ((a0 + a1) + (a2 + a3)) * inv + bv[lane];
}

// ---------------------------------------------------------------------------
extern "C" void kernel_launch(void* const* d_in, const int* in_sizes, int n_in,
                              void* d_out, int out_size, void* d_ws, size_t ws_size,
                              hipStream_t stream) {
    const float* h_obs     = (const float*)d_in[0];
    // d_in[1] = x_obs (unused by reference)
    const float* pos_obs   = (const float*)d_in[2];
    const float* pos_query = (const float*)d_in[3];
    const float* W1        = (const float*)d_in[4];
    const float* b1        = (const float*)d_in[5];
    const float* W2        = (const float*)d_in[6];
    // d_in[7] = b2: constant shift, cancels in softmax
    const float* Wv        = (const float*)d_in[8];
    const float* bv        = (const float*)d_in[9];
    float* ws  = (float*)d_ws;
    float* out = (float*)d_out;

    gano_prep<<<dim3(NO * 64 / 256), dim3(256), 0, stream>>>(pos_obs, W1, ws + OFF_TT);
    gano_main<<<dim3(1024), dim3(256), 0, stream>>>(ws + OFF_TT, h_obs, pos_obs, pos_query,
                                                    W1, b1, W2, ws + OFF_PH, ws + OFF_PS);
    gano_comb<<<dim3(NQ / 4), dim3(256), 0, stream>>>(ws + OFF_PH, ws + OFF_PS, Wv, bv, out);
}